// Round 4
// baseline (81.348 us; speedup 1.0000x reference)
//
#include <hip/hip_runtime.h>

// YibeiVessels: fused per-voxel LUT gather + onehot channel synthesis.
// out layout (flat f32): [ out_vol (V) | ch0 (V) | ch1 (V) | ch2 (V) ], V = 256^3.
//
// R3: 2x unroll with load-ahead (4 nt-loads in flight per thread before any
// compute/store) to raise read MLP; nt loads/stores kept from R2.

#define N_IDS 257
#define VOL (256 * 256 * 256)

typedef float f32x4 __attribute__((ext_vector_type(4)));
typedef int   i32x4 __attribute__((ext_vector_type(4)));

__global__ __launch_bounds__(256) void YibeiVessels_74156905333425_kernel(
    const int* __restrict__ labels,
    const float* __restrict__ intensities,
    const int* __restrict__ class_bits,
    const float* __restrict__ parenchyma,
    float* __restrict__ out)
{
    // Pre-fused LUTs in LDS (2 KB total):
    //   s_scale[id] : scaling factor (1.0 for background id 0)
    //   s_c1[id]    : 1.0 iff vessel (id>0) and class_bits[id]==0
    // Channels: ch0 = 1 - is_vessel; ch2 = is_vessel - ch1.
    __shared__ float s_scale[N_IDS];
    __shared__ float s_c1[N_IDS];

    const int tid = threadIdx.x;
    for (int i = tid; i < N_IDS; i += 256) {
        const float inten = intensities[i];
        const int cb = class_bits[i];
        const bool vessel = (i > 0);
        s_scale[i] = vessel ? inten : 1.0f;
        s_c1[i] = (vessel && cb == 0) ? 1.0f : 0.0f;
    }
    __syncthreads();

    const int nquads = VOL / 4;                       // 4,194,304 float4 groups
    const int stride = gridDim.x * blockDim.x;        // 524,288 threads

    const i32x4* lab4 = reinterpret_cast<const i32x4*>(labels);
    const f32x4* par4 = reinterpret_cast<const f32x4*>(parenchyma);
    f32x4* vol4 = reinterpret_cast<f32x4*>(out);
    f32x4* c04  = reinterpret_cast<f32x4*>(out + (size_t)VOL);
    f32x4* c14  = reinterpret_cast<f32x4*>(out + 2 * (size_t)VOL);
    f32x4* c24  = reinterpret_cast<f32x4*>(out + 3 * (size_t)VOL);

    const int gid = blockIdx.x * blockDim.x + tid;

    for (int q0 = gid; q0 < nquads; q0 += 2 * stride) {
        const int q1 = q0 + stride;

        // Issue all 4 loads up front (each is a perfectly coalesced 1 KB
        // wave transaction); compute only after both pairs are in flight.
        const i32x4 labA = __builtin_nontemporal_load(&lab4[q0]);
        const f32x4 parA = __builtin_nontemporal_load(&par4[q0]);
        const i32x4 labB = __builtin_nontemporal_load(&lab4[q1]);
        const f32x4 parB = __builtin_nontemporal_load(&par4[q1]);

        f32x4 volA, c0A, c1A, c2A;
        #pragma unroll
        for (int e = 0; e < 4; ++e) {
            const int l = labA[e];
            const float vf = (l > 0) ? 1.0f : 0.0f;
            volA[e] = parA[e] * s_scale[l];
            c1A[e] = s_c1[l];
            c0A[e] = 1.0f - vf;
            c2A[e] = vf - c1A[e];
        }
        __builtin_nontemporal_store(volA, &vol4[q0]);
        __builtin_nontemporal_store(c0A, &c04[q0]);
        __builtin_nontemporal_store(c1A, &c14[q0]);
        __builtin_nontemporal_store(c2A, &c24[q0]);

        f32x4 volB, c0B, c1B, c2B;
        #pragma unroll
        for (int e = 0; e < 4; ++e) {
            const int l = labB[e];
            const float vf = (l > 0) ? 1.0f : 0.0f;
            volB[e] = parB[e] * s_scale[l];
            c1B[e] = s_c1[l];
            c0B[e] = 1.0f - vf;
            c2B[e] = vf - c1B[e];
        }
        __builtin_nontemporal_store(volB, &vol4[q1]);
        __builtin_nontemporal_store(c0B, &c04[q1]);
        __builtin_nontemporal_store(c1B, &c14[q1]);
        __builtin_nontemporal_store(c2B, &c24[q1]);
    }
}

extern "C" void kernel_launch(void* const* d_in, const int* in_sizes, int n_in,
                              void* d_out, int out_size, void* d_ws, size_t ws_size,
                              hipStream_t stream) {
    const int*   labels      = (const int*)d_in[0];
    const float* intensities = (const float*)d_in[1];
    const int*   class_bits  = (const int*)d_in[2];
    const float* parenchyma  = (const float*)d_in[3];
    float* out = (float*)d_out;

    const int blocks = 2048;   // 256 CUs x 8 blocks; 4 iterations of 2 quads/thread
    YibeiVessels_74156905333425_kernel<<<blocks, 256, 0, stream>>>(
        labels, intensities, class_bits, parenchyma, out);
}

// Round 5
// 78.752 us; speedup vs baseline: 1.0330x; 1.0330x over previous
//
#include <hip/hip_runtime.h>

// YibeiVessels: fused per-voxel LUT gather + onehot channel synthesis.
// out layout (flat f32): [ out_vol (V) | ch0 (V) | ch1 (V) | ch2 (V) ], V = 256^3.
//
// R4: revert R3's stride-apart unroll (regressed -4%: full occupancy means TLP
// already covers latency; unroll only perturbed scheduling). Keep R2 structure,
// pack both LUTs into ONE f32 (sign bit = dark-vessel flag; intensities are
// non-negative so the sign bit is free) -> 1 ds_read_b32 gather per voxel
// instead of 2, halving LDS bank-conflict exposure. Bit-exact unpack.

#define N_IDS 257
#define VOL (256 * 256 * 256)

typedef float f32x4 __attribute__((ext_vector_type(4)));
typedef int   i32x4 __attribute__((ext_vector_type(4)));

__global__ __launch_bounds__(256) void YibeiVessels_74156905333425_kernel(
    const int* __restrict__ labels,
    const float* __restrict__ intensities,
    const int* __restrict__ class_bits,
    const float* __restrict__ parenchyma,
    float* __restrict__ out)
{
    // Packed LUT: bits[30:0] = scaling factor (1.0 for background id 0;
    // intensities are in [0,2) so always non-negative), bit[31] = 1 iff
    // vessel AND class_bits==0 (i.e. this voxel belongs in channel 1).
    __shared__ unsigned s_lut[N_IDS];

    const int tid = threadIdx.x;
    for (int i = tid; i < N_IDS; i += 256) {
        const float inten = intensities[i];
        const int cb = class_bits[i];
        const bool vessel = (i > 0);
        unsigned bits = __float_as_uint(vessel ? inten : 1.0f);
        if (vessel && cb == 0) bits |= 0x80000000u;
        s_lut[i] = bits;
    }
    __syncthreads();

    const int nquads = VOL / 4;                       // 4,194,304 float4 groups
    const int stride = gridDim.x * blockDim.x;

    const i32x4* lab4 = reinterpret_cast<const i32x4*>(labels);
    const f32x4* par4 = reinterpret_cast<const f32x4*>(parenchyma);
    f32x4* vol4 = reinterpret_cast<f32x4*>(out);
    f32x4* c04  = reinterpret_cast<f32x4*>(out + (size_t)VOL);
    f32x4* c14  = reinterpret_cast<f32x4*>(out + 2 * (size_t)VOL);
    f32x4* c24  = reinterpret_cast<f32x4*>(out + 3 * (size_t)VOL);

    for (int q = blockIdx.x * blockDim.x + tid; q < nquads; q += stride) {
        const i32x4 lab = __builtin_nontemporal_load(&lab4[q]);
        const f32x4 par = __builtin_nontemporal_load(&par4[q]);

        f32x4 vol, c0, c1, c2;

        #pragma unroll
        for (int e = 0; e < 4; ++e) {
            const int l = lab[e];
            const unsigned bits = s_lut[l];
            const float scale = __uint_as_float(bits & 0x7fffffffu);
            const float is_c1 = (float)(bits >> 31);           // 1.0 iff dark vessel
            const float vf = (l > 0) ? 1.0f : 0.0f;
            vol[e] = par[e] * scale;
            c0[e] = 1.0f - vf;
            c1[e] = is_c1;
            c2[e] = vf - is_c1;
        }

        __builtin_nontemporal_store(vol, &vol4[q]);
        __builtin_nontemporal_store(c0, &c04[q]);
        __builtin_nontemporal_store(c1, &c14[q]);
        __builtin_nontemporal_store(c2, &c24[q]);
    }
}

extern "C" void kernel_launch(void* const* d_in, const int* in_sizes, int n_in,
                              void* d_out, int out_size, void* d_ws, size_t ws_size,
                              hipStream_t stream) {
    const int*   labels      = (const int*)d_in[0];
    const float* intensities = (const float*)d_in[1];
    const int*   class_bits  = (const int*)d_in[2];
    const float* parenchyma  = (const float*)d_in[3];
    float* out = (float*)d_out;

    const int blocks = 2048;   // 256 CUs x 8 blocks; grid-stride covers 4.19M quads
    YibeiVessels_74156905333425_kernel<<<blocks, 256, 0, stream>>>(
        labels, intensities, class_bits, parenchyma, out);
}